// Round 1
// baseline (295.432 us; speedup 1.0000x reference)
//
#include <hip/hip_runtime.h>

// VecANDTree: x (65536,1024) f32 in {0,1}; out[row] = AND of all 1024 bits.
// AND-tree with threshold 1.5 on {0,1} inputs == logical AND (1024 is a power
// of two so the odd-carry path in the reference never triggers).
//
// Strategy: one 64-lane wave per row. Lane i checks element i of the row
// (coalesced 256B read). If any of the first 64 bits is 0 (prob 1 - 2^-64),
// the row is resolved having read only 256B of its 4KiB. Early exit is
// semantically exact: AND with an observed 0 is 0 regardless of the rest.
// Rare all-ones prefix falls through to a cold loop over remaining chunks.

#define COLS 1024
#define WAVES_PER_BLOCK 4

__global__ __launch_bounds__(256) void VecANDTree_43860206027289_kernel(
    const float* __restrict__ x, float* __restrict__ out, int rows) {
    const int lane = threadIdx.x & 63;
    const int row = blockIdx.x * WAVES_PER_BLOCK + (threadIdx.x >> 6);
    if (row >= rows) return;

    const float* rp = x + (size_t)row * COLS;

    // Hot path: first 64 elements, one per lane, coalesced.
    bool ok = rp[lane] > 0.5f;
    if (__builtin_expect(!__all(ok), 1)) {
        if (lane == 0) out[row] = 0.0f;
        return;
    }

    // Cold path (prob ~2^-64 per row): scan remaining chunks.
    float r = 1.0f;
#pragma unroll 1
    for (int c = 1; c < COLS / 64; ++c) {
        ok = rp[c * 64 + lane] > 0.5f;
        if (!__all(ok)) { r = 0.0f; break; }
    }
    if (lane == 0) out[row] = r;
}

extern "C" void kernel_launch(void* const* d_in, const int* in_sizes, int n_in,
                              void* d_out, int out_size, void* d_ws, size_t ws_size,
                              hipStream_t stream) {
    const float* x = (const float*)d_in[0];
    float* out = (float*)d_out;
    const int rows = out_size;            // 65536
    const int blocks = (rows + WAVES_PER_BLOCK - 1) / WAVES_PER_BLOCK;  // 16384
    VecANDTree_43860206027289_kernel<<<blocks, 256, 0, stream>>>(x, out, rows);
}

// Round 2
// 292.191 us; speedup vs baseline: 1.0111x; 1.0111x over previous
//
#include <hip/hip_runtime.h>

// VecANDTree: x (65536,1024) f32 in {0,1}; out[row] = AND of all 1024 bits.
// (1024 = 2^10 so the reference's odd-carry path never triggers; threshold
// a+b>1.5 on {0,1} == logical AND.)
//
// R2 strategy: 16-lane prefix probe per row (64 B = one cache line, the
// minimum HBM granule). P(first 16 bits all 1) = 2^-16, so ~1 row per call
// needs the exact wave-cooperative full scan — semantics stay exact.
// Each wave handles 32 rows: 8 independent loads (4 rows x 16 lanes each)
// issued back-to-back for ILP, ballot-resolved, then ONE coalesced 128 B
// store (lanes 0..31). Grid: 512 blocks x 256 threads.

#define COLS 1024
#define ROWS_PER_WAVE 32
#define LOADS_PER_WAVE (ROWS_PER_WAVE / 4)   // 8 loads, 4 rows each
#define THREADS 256
#define WAVES_PER_BLOCK (THREADS / 64)

__device__ __forceinline__ float full_row_scan(const float* __restrict__ rp,
                                               int lane) {
    // Exact AND over all 1024 elements, wave-cooperative coalesced chunks.
#pragma unroll 1
    for (int c = 0; c < COLS / 64; ++c) {
        if (!__all(rp[c * 64 + lane] > 0.5f)) return 0.0f;
    }
    return 1.0f;
}

__global__ __launch_bounds__(THREADS) void VecANDTree_43860206027289_kernel(
    const float* __restrict__ x, float* __restrict__ out, int rows) {
    const int lane = threadIdx.x & 63;
    const int wave = blockIdx.x * WAVES_PER_BLOCK + (threadIdx.x >> 6);
    const int base = wave * ROWS_PER_WAVE;
    if (base >= rows) return;

    const int sub = lane >> 4;                       // which of 4 rows in a load
    const int col = lane & 15;                       // prefix column 0..15
    const size_t lane_off = (size_t)sub * COLS + col;
    const float* bp = x + (size_t)base * COLS + lane_off;

    // 8 independent prefix loads: load l covers rows base+4l .. base+4l+3,
    // 64 B contiguous per row (aligned cache line).
    float v[LOADS_PER_WAVE];
#pragma unroll
    for (int l = 0; l < LOADS_PER_WAVE; ++l) {
        v[l] = bp[(size_t)l * 4 * COLS];
    }

    float res = 0.0f;
#pragma unroll
    for (int l = 0; l < LOADS_PER_WAVE; ++l) {
        const unsigned long long m = __ballot(v[l] > 0.5f);
#pragma unroll
        for (int g = 0; g < 4; ++g) {
            const bool pass = ((m >> (16 * g)) & 0xFFFFull) == 0xFFFFull; // uniform
            float r = 0.0f;
            if (pass) {  // rare: P = 2^-16 per row -> exact full scan
                r = full_row_scan(x + (size_t)(base + 4 * l + g) * COLS, lane);
            }
            if (lane == 4 * l + g) res = r;
        }
    }

    // One coalesced 128 B store per wave.
    if (lane < ROWS_PER_WAVE) out[base + lane] = res;
}

extern "C" void kernel_launch(void* const* d_in, const int* in_sizes, int n_in,
                              void* d_out, int out_size, void* d_ws, size_t ws_size,
                              hipStream_t stream) {
    const float* x = (const float*)d_in[0];
    float* out = (float*)d_out;
    const int rows = out_size;                                   // 65536
    const int waves = (rows + ROWS_PER_WAVE - 1) / ROWS_PER_WAVE; // 2048
    const int blocks = (waves + WAVES_PER_BLOCK - 1) / WAVES_PER_BLOCK; // 512
    VecANDTree_43860206027289_kernel<<<blocks, THREADS, 0, stream>>>(x, out, rows);
}